// Round 3
// baseline (156.929 us; speedup 1.0000x reference)
//
#include <hip/hip_runtime.h>

#define BATCH 512
#define SEQL  512
#define EMBD  100
#define NCH   14
#define NCLS  5
#define NPAIR 54          // sum of kernel sizes 2+2+3+3+3+4*4+5*5
#define WSF   5400        // 25 q-chunks * 54 pairs * 4 floats

// channel -> kernel size, pair-base, group, o-within-group (compile-time)
__device__ __constant__ int d_dummy; // keep TU non-empty of constants (unused)

// ---------------- repack kernel: weights -> ws[q][pair][4], bias -> ws[5400..5413]
__global__ void repack_w(
    const float* __restrict__ w2, const float* __restrict__ b2,
    const float* __restrict__ w3, const float* __restrict__ b3,
    const float* __restrict__ w4, const float* __restrict__ b4,
    const float* __restrict__ w5, const float* __restrict__ b5,
    float* __restrict__ ws)
{
    constexpr int KC[NCH]    = {2,2, 3,3,3, 4,4,4,4, 5,5,5,5,5};
    constexpr int PBASE[NCH] = {0,2, 4,7,10, 13,17,21,25, 29,34,39,44,49};
    constexpr int GRP[NCH]   = {0,0, 1,1,1, 2,2,2,2, 3,3,3,3,3};
    constexpr int OIN[NCH]   = {0,1, 0,1,2, 0,1,2,3, 0,1,2,3,4};
    constexpr int PAIR_C[NPAIR] = {0,0, 1,1, 2,2,2, 3,3,3, 4,4,4,
                                   5,5,5,5, 6,6,6,6, 7,7,7,7, 8,8,8,8,
                                   9,9,9,9,9, 10,10,10,10,10, 11,11,11,11,11,
                                   12,12,12,12,12, 13,13,13,13,13};
    const float* WP[4] = {w2, w3, w4, w5};
    const int tid = threadIdx.x;

    for (int i = tid; i < WSF; i += 256) {
        int q   = i / (NPAIR * 4);
        int rem = i - q * (NPAIR * 4);
        int p   = rem >> 2;
        int r   = rem & 3;
        int c   = PAIR_C[p];
        int j   = p - PBASE[c];
        int k   = KC[c];
        int o   = OIN[c];
        int dd  = q * 4 + r;
        ws[i] = WP[GRP[c]][(o * EMBD + dd) * k + j];
    }
    if (tid < NCH) {
        ws[WSF + tid] = (tid < 2) ? b2[tid] : (tid < 5) ? b3[tid - 2]
                      : (tid < 9) ? b4[tid - 5] : b5[tid - 9];
    }
}

// ---------------- main kernel: 1 block per batch row, 512 threads, P=1 position/thread
__global__ __launch_bounds__(512, 4) void cnn_fused(
    const int* __restrict__ words,
    const float* __restrict__ emb,
    const float* __restrict__ ws,      // repacked weights (read-only, uniform access)
    const float* __restrict__ fcw, const float* __restrict__ fcb,
    float* __restrict__ out)
{
    constexpr int KC[NCH]    = {2,2, 3,3,3, 4,4,4,4, 5,5,5,5,5};
    constexpr int PBASE[NCH] = {0,2, 4,7,10, 13,17,21,25, 29,34,39,44,49};

    __shared__ float red[8][NCH];

    const int b   = blockIdx.x;
    const int tid = threadIdx.x;     // = position t
    const int t   = tid;

    // ---- token rows t..t+4 (clamped; clamped rows feed only masked outputs) ----
    int tok[5];
    #pragma unroll
    for (int r = 0; r < 5; ++r) {
        int u = t + r;
        tok[r] = (u < SEQL) ? words[b * SEQL + u] : 0;
    }
    const float4* __restrict__ emb4 = reinterpret_cast<const float4*>(emb);
    const float4* rowp[5];
    #pragma unroll
    for (int r = 0; r < 5; ++r) rowp[r] = emb4 + (long)tok[r] * 25;

    const float4* __restrict__ ws4 = reinterpret_cast<const float4*>(ws);

    float y[NCH];
    #pragma unroll
    for (int c = 0; c < NCH; ++c) y[c] = 0.f;

    // FMA block over one 4-float d-chunk; weight reads are wave-uniform -> s_load
    auto compute = [&](const float4 (&xr)[5], int q) {
        const float4* wq = ws4 + q * NPAIR;
        #pragma unroll
        for (int c = 0; c < NCH; ++c) {
            #pragma unroll
            for (int j = 0; j < 5; ++j) {
                if (j < KC[c]) {                       // compile-time folded
                    const float4 wv = wq[PBASE[c] + j]; // contiguous p-order
                    y[c] += xr[j].x * wv.x;
                    y[c] += xr[j].y * wv.y;
                    y[c] += xr[j].z * wv.z;
                    y[c] += xr[j].w * wv.w;
                }
            }
        }
    };

    // ---- software-pipelined q-loop (2-deep register double buffer) ----
    float4 xA[5], xB[5];
    #pragma unroll
    for (int r = 0; r < 5; ++r) xA[r] = rowp[r][0];

    #pragma unroll 1
    for (int q = 0; q < 24; q += 2) {
        #pragma unroll
        for (int r = 0; r < 5; ++r) xB[r] = rowp[r][q + 1];
        compute(xA, q);
        #pragma unroll
        for (int r = 0; r < 5; ++r) xA[r] = rowp[r][q + 2];
        compute(xB, q + 1);
    }
    compute(xA, 24);

    // ---- bias + relu (valid positions only), then 64-lane max reduce ----
    float m[NCH];
    #pragma unroll
    for (int c = 0; c < NCH; ++c) {
        float v = 0.f;                        // relu floor doubles as -inf substitute
        if (t + KC[c] <= SEQL)
            v = fmaxf(v, y[c] + ws[WSF + c]); // uniform scalar bias load
        m[c] = v;
    }
    #pragma unroll
    for (int c = 0; c < NCH; ++c) {
        float v = m[c];
        #pragma unroll
        for (int off = 32; off > 0; off >>= 1)
            v = fmaxf(v, __shfl_xor(v, off, 64));
        m[c] = v;
    }
    const int wave = tid >> 6;
    const int lane = tid & 63;
    if (lane == 0) {
        #pragma unroll
        for (int c = 0; c < NCH; ++c) red[wave][c] = m[c];
    }
    __syncthreads();

    // ---- FC ----
    if (tid < NCLS) {
        float acc = fcb[tid];
        #pragma unroll
        for (int o = 0; o < NCH; ++o) {
            float f = red[0][o];
            #pragma unroll
            for (int w = 1; w < 8; ++w) f = fmaxf(f, red[w][o]);
            acc += fcw[tid * NCH + o] * f;
        }
        out[b * NCLS + tid] = acc;
    }
}

extern "C" void kernel_launch(void* const* d_in, const int* in_sizes, int n_in,
                              void* d_out, int out_size, void* d_ws, size_t ws_size,
                              hipStream_t stream) {
    const int*   words = (const int*)  d_in[0];
    const float* emb   = (const float*)d_in[1];
    const float* w2    = (const float*)d_in[2];
    const float* b2    = (const float*)d_in[3];
    const float* w3    = (const float*)d_in[4];
    const float* b3    = (const float*)d_in[5];
    const float* w4    = (const float*)d_in[6];
    const float* b4    = (const float*)d_in[7];
    const float* w5    = (const float*)d_in[8];
    const float* b5    = (const float*)d_in[9];
    const float* fcw   = (const float*)d_in[10];
    const float* fcb   = (const float*)d_in[11];
    float* out = (float*)d_out;
    float* ws  = (float*)d_ws;

    hipLaunchKernelGGL(repack_w, dim3(1), dim3(256), 0, stream,
                       w2, b2, w3, b3, w4, b4, w5, b5, ws);
    hipLaunchKernelGGL(cnn_fused, dim3(BATCH), dim3(512), 0, stream,
                       words, emb, ws, fcw, fcb, out);
}

// Round 4
// 63.309 us; speedup vs baseline: 2.4788x; 2.4788x over previous
//
#include <hip/hip_runtime.h>
#include <hip/hip_bf16.h>

#define BATCH 512
#define SEQL  512
#define NCH   14
#define NCLS  5
#define DPAD  128          // padded emb dim (d=100..127 zeros)
#define KSTEPS 20          // K = 5*128 / 32
#define POSB  128          // positions per block
#define ROWS  132          // POSB + 4 halo
#define WS_B_BYTES 20480   // 20 ksteps * 64 lanes * 16 B  (B fragments, bf16)
#define BIAS_OFF   20480   // f32[16]
#define FEAT_OFF   20544   // f32[2048*16]

typedef __attribute__((ext_vector_type(8))) short bf16x8;
typedef __attribute__((ext_vector_type(4))) float f32x4;

static __device__ __forceinline__ unsigned short bf16bits(float f) {
    __hip_bfloat16 h = __float2bfloat16(f);
    return __builtin_bit_cast(unsigned short, h);
}

// ---------------- repack: conv weights -> MFMA B-fragment layout (bf16) + biases
// B[k][n]: k = j*128 + d (tap j, dim d), n = channel. Lane l holds n=l&15,
// k = kstep*32 + (l>>4)*8 + e, e=0..7. ws element i = (kstep*64 + l)*8 + e.
__global__ void repack_w(
    const float* __restrict__ w2, const float* __restrict__ b2,
    const float* __restrict__ w3, const float* __restrict__ b3,
    const float* __restrict__ w4, const float* __restrict__ b4,
    const float* __restrict__ w5, const float* __restrict__ b5,
    unsigned short* __restrict__ wsb, float* __restrict__ biasf)
{
    const float* WP[4] = {w2, w3, w4, w5};
    const int tid = threadIdx.x;
    for (int i = tid; i < WS_B_BYTES / 2; i += 256) {
        int kstep = i >> 9;          // / (64*8)
        int rem   = i & 511;
        int l     = rem >> 3;
        int e     = rem & 7;
        int k     = kstep * 32 + ((l >> 4) << 3) + e;
        int n     = l & 15;
        int j     = k >> 7;          // tap
        int d     = k & 127;         // emb dim
        float v = 0.f;
        if (n < NCH && d < 100) {
            int kc = 2 + (n >= 2) + (n >= 5) + (n >= 9);
            if (j < kc) {
                int grp = (n >= 2) + (n >= 5) + (n >= 9);
                int ob  = (grp == 0) ? 0 : (grp == 1) ? 2 : (grp == 2) ? 5 : 9;
                v = WP[grp][((n - ob) * 100 + d) * kc + j];
            }
        }
        wsb[i] = bf16bits(v);
    }
    if (tid < 16) {
        float bv = 0.f;
        if (tid < 2)        bv = b2[tid];
        else if (tid < 5)   bv = b3[tid - 2];
        else if (tid < 9)   bv = b4[tid - 5];
        else if (tid < NCH) bv = b5[tid - 9];
        biasf[tid] = bv;
    }
}

// ---------------- main: 2048 blocks = 4 per batch row, 256 threads (4 waves)
// Stage X[132][128] bf16 into LDS (XOR-swizzled), MFMA 16x16x32 over K=640,
// fused bias+relu+masked max; per-block 16 feats -> ws.
__global__ __launch_bounds__(256, 3) void cnn_mfma(
    const int* __restrict__ words,
    const float* __restrict__ emb,
    const char* __restrict__ ws,
    float* __restrict__ feats)
{
    __shared__ unsigned short xs[ROWS * DPAD];   // 33792 B, swizzled
    __shared__ float red[4][16];

    const int bid = blockIdx.x;
    const int b   = bid >> 2;
    const int blk = bid & 3;
    const int p0  = blk * POSB;
    const int tid = threadIdx.x;
    const int l   = tid & 63;
    const int wv  = tid >> 6;

    // ---- B fragments: 20 coalesced dwordx4 per lane, once ----
    bf16x8 bfrag[KSTEPS];
    #pragma unroll
    for (int ks = 0; ks < KSTEPS; ++ks)
        bfrag[ks] = *reinterpret_cast<const bf16x8*>(ws + (ks * 64 + l) * 16);

    // ---- stage X: pass 1: rows 0..127, 2 threads/row, 16 chunks each ----
    const float4* __restrict__ emb4 = reinterpret_cast<const float4*>(emb);
    uint2* xs2 = reinterpret_cast<uint2*>(xs);
    {
        const int r    = tid >> 1;
        const int half = tid & 1;
        const int t    = p0 + r;
        const bool live = (t < SEQL);
        const int tok  = live ? words[b * SEQL + t] : 0;
        #pragma unroll
        for (int qq = 0; qq < 16; ++qq) {
            const int q = half * 16 + qq;
            uint lo = 0, hi = 0;
            if (live && q < 25) {
                float4 x = emb4[(long)tok * 25 + q];
                lo = (uint)bf16bits(x.x) | ((uint)bf16bits(x.y) << 16);
                hi = (uint)bf16bits(x.z) | ((uint)bf16bits(x.w) << 16);
            }
            const int addr = (r * 256 + q * 8) ^ ((r & 7) << 4);
            xs2[addr >> 3] = make_uint2(lo, hi);
        }
    }
    // ---- pass 2: rows 128..131, 1 chunk/thread ----
    if (tid < 128) {
        const int r = 128 + (tid >> 5);
        const int q = tid & 31;
        const int t = p0 + r;
        uint lo = 0, hi = 0;
        if (t < SEQL && q < 25) {
            int tok = words[b * SEQL + t];
            float4 x = emb4[(long)tok * 25 + q];
            lo = (uint)bf16bits(x.x) | ((uint)bf16bits(x.y) << 16);
            hi = (uint)bf16bits(x.z) | ((uint)bf16bits(x.w) << 16);
        }
        const int addr = (r * 256 + q * 8) ^ ((r & 7) << 4);
        xs2[addr >> 3] = make_uint2(lo, hi);
    }
    __syncthreads();

    // ---- MFMA: wave computes 32 positions x 16 channels, K=640 ----
    f32x4 acc0 = {0.f, 0.f, 0.f, 0.f};
    f32x4 acc1 = {0.f, 0.f, 0.f, 0.f};
    const int m0 = wv * 32 + (l & 15);
    const int dl = (l >> 4) << 3;                // k-slice d-offset: 0,8,16,24
    const char* xsb = reinterpret_cast<const char*>(xs);
    #pragma unroll
    for (int ks = 0; ks < KSTEPS; ++ks) {
        const int j  = ks >> 2;
        const int d0 = ((ks & 3) << 5) + dl;
        const int row0 = m0 + j;
        const int a0ad = (row0 * 256 + d0 * 2) ^ ((row0 & 7) << 4);
        const int row1 = row0 + 16;
        const int a1ad = (row1 * 256 + d0 * 2) ^ ((row1 & 7) << 4);
        bf16x8 a0 = *reinterpret_cast<const bf16x8*>(xsb + a0ad);
        bf16x8 a1 = *reinterpret_cast<const bf16x8*>(xsb + a1ad);
        acc0 = __builtin_amdgcn_mfma_f32_16x16x32_bf16(a0, bfrag[ks], acc0, 0, 0, 0);
        acc1 = __builtin_amdgcn_mfma_f32_16x16x32_bf16(a1, bfrag[ks], acc1, 0, 0, 0);
    }

    // ---- bias + relu + masked max over this wave's 8 (pos) rows ----
    const int ch  = l & 15;
    const int kch = 2 + (ch >= 2) + (ch >= 5) + (ch >= 9);
    const float bias = *reinterpret_cast<const float*>(ws + BIAS_OFF + ch * 4);
    const int rbase = (l >> 4) << 2;
    float v = 0.f;
    #pragma unroll
    for (int r = 0; r < 4; ++r) {
        const int t0 = p0 + wv * 32 + rbase + r;       // C row = (lane>>4)*4+reg
        if (t0 + kch <= SEQL) v = fmaxf(v, fmaxf(acc0[r] + bias, 0.f));
        const int t1 = t0 + 16;
        if (t1 + kch <= SEQL) v = fmaxf(v, fmaxf(acc1[r] + bias, 0.f));
    }
    v = fmaxf(v, __shfl_xor(v, 16, 64));
    v = fmaxf(v, __shfl_xor(v, 32, 64));
    if (l < 16) red[wv][ch] = v;
    __syncthreads();

    if (tid < 16) {
        float f = fmaxf(fmaxf(red[0][tid], red[1][tid]),
                        fmaxf(red[2][tid], red[3][tid]));
        feats[bid * 16 + tid] = f;
    }
}

// ---------------- FC: combine 4 block-partials per row, tiny GEMV
__global__ void fc_kernel(const float* __restrict__ feats,
                          const float* __restrict__ fcw,
                          const float* __restrict__ fcb,
                          float* __restrict__ out)
{
    const int i = blockIdx.x * 256 + threadIdx.x;
    if (i >= BATCH * NCLS) return;
    const int b   = i / NCLS;
    const int cls = i - b * NCLS;
    const float* fb = feats + b * 64;
    float acc = fcb[cls];
    #pragma unroll
    for (int o = 0; o < NCH; ++o) {
        float f = fmaxf(fmaxf(fb[o], fb[16 + o]), fmaxf(fb[32 + o], fb[48 + o]));
        acc += fcw[cls * NCH + o] * f;
    }
    out[i] = acc;
}

extern "C" void kernel_launch(void* const* d_in, const int* in_sizes, int n_in,
                              void* d_out, int out_size, void* d_ws, size_t ws_size,
                              hipStream_t stream) {
    const int*   words = (const int*)  d_in[0];
    const float* emb   = (const float*)d_in[1];
    const float* w2    = (const float*)d_in[2];
    const float* b2    = (const float*)d_in[3];
    const float* w3    = (const float*)d_in[4];
    const float* b3    = (const float*)d_in[5];
    const float* w4    = (const float*)d_in[6];
    const float* b4    = (const float*)d_in[7];
    const float* w5    = (const float*)d_in[8];
    const float* b5    = (const float*)d_in[9];
    const float* fcw   = (const float*)d_in[10];
    const float* fcb   = (const float*)d_in[11];
    float* out = (float*)d_out;
    char*  ws  = (char*)d_ws;

    unsigned short* wsb  = (unsigned short*)ws;
    float* biasf = (float*)(ws + BIAS_OFF);
    float* feats = (float*)(ws + FEAT_OFF);

    hipLaunchKernelGGL(repack_w, dim3(1), dim3(256), 0, stream,
                       w2, b2, w3, b3, w4, b4, w5, b5, wsb, biasf);
    hipLaunchKernelGGL(cnn_mfma, dim3(BATCH * 4), dim3(256), 0, stream,
                       words, emb, ws, feats);
    hipLaunchKernelGGL(fc_kernel, dim3((BATCH * NCLS + 255) / 256), dim3(256), 0, stream,
                       feats, fcw, fcb, out);
}

// Round 5
// 41.387 us; speedup vs baseline: 3.7918x; 1.5297x over previous
//
#include <hip/hip_runtime.h>
#include <hip/hip_bf16.h>

#define BATCH 512
#define SEQL  512
#define NCH   14
#define NCLS  5
#define DPAD  128          // padded emb dim (d=100..127 zeros)
#define KSTEPS 20          // K = 5*128 / 32
#define POSB  64           // positions per block
#define ROWS  68           // POSB + 4 halo
#define BLKS_PER_ROW 8
#define NBLK  (BATCH * BLKS_PER_ROW)
#define WS_B_BYTES 20480   // 20 ksteps * 64 lanes * 16 B  (B fragments, bf16)
#define BIAS_OFF   20480   // f32[16]
#define FEAT_OFF   20544   // f32[NBLK*16]

typedef __attribute__((ext_vector_type(8))) short bf16x8;
typedef __attribute__((ext_vector_type(4))) float f32x4;

static __device__ __forceinline__ unsigned short bf16bits(float f) {
    __hip_bfloat16 h = __float2bfloat16(f);
    return __builtin_bit_cast(unsigned short, h);
}

// ---------------- repack: conv weights -> MFMA B-fragment layout (bf16) + biases
// B[k][n]: k = j*128 + d (tap j, dim d), n = channel. Lane l holds n=l&15,
// k = kstep*32 + (l>>4)*8 + e, e=0..7. ws element i = (kstep*64 + l)*8 + e.
// Parallel: 40 blocks x 256 threads = 10240 = WS_B_BYTES/2 elements.
__global__ void repack_w(
    const float* __restrict__ w2, const float* __restrict__ b2,
    const float* __restrict__ w3, const float* __restrict__ b3,
    const float* __restrict__ w4, const float* __restrict__ b4,
    const float* __restrict__ w5, const float* __restrict__ b5,
    unsigned short* __restrict__ wsb, float* __restrict__ biasf)
{
    const float* WP[4] = {w2, w3, w4, w5};
    const int i = blockIdx.x * 256 + threadIdx.x;
    if (i < WS_B_BYTES / 2) {
        int kstep = i >> 9;          // / (64*8)
        int rem   = i & 511;
        int l     = rem >> 3;
        int e     = rem & 7;
        int k     = kstep * 32 + ((l >> 4) << 3) + e;
        int n     = l & 15;
        int j     = k >> 7;          // tap
        int d     = k & 127;         // emb dim
        float v = 0.f;
        if (n < NCH && d < 100) {
            int kc = 2 + (n >= 2) + (n >= 5) + (n >= 9);
            if (j < kc) {
                int grp = (n >= 2) + (n >= 5) + (n >= 9);
                int ob  = (grp == 0) ? 0 : (grp == 1) ? 2 : (grp == 2) ? 5 : 9;
                v = WP[grp][((n - ob) * 100 + d) * kc + j];
            }
        }
        wsb[i] = bf16bits(v);
    }
    if (blockIdx.x == 0 && threadIdx.x < 16) {
        const int t = threadIdx.x;
        float bv = 0.f;
        if (t < 2)        bv = b2[t];
        else if (t < 5)   bv = b3[t - 2];
        else if (t < 9)   bv = b4[t - 5];
        else if (t < NCH) bv = b5[t - 9];
        biasf[t] = bv;
    }
}

// ---------------- main: 4096 blocks = 8 per batch row, 256 threads (4 waves)
// Stage X[68][128] bf16 into LDS (XOR-swizzled), MFMA 16x16x32 over K=640,
// fused bias+relu+masked max; per-block 16 feats -> ws.
__global__ __launch_bounds__(256, 8) void cnn_mfma(
    const int* __restrict__ words,
    const float* __restrict__ emb,
    const char* __restrict__ ws,
    float* __restrict__ feats)
{
    __shared__ unsigned short xs[ROWS * DPAD];   // 17408 B, swizzled
    __shared__ float red[4][16];

    const int bid = blockIdx.x;
    const int b   = bid >> 3;
    const int blk = bid & 7;
    const int p0  = blk * POSB;
    const int tid = threadIdx.x;
    const int l   = tid & 63;
    const int wv  = tid >> 6;

    // ---- stage X: flat chunk loop, r=i>>5 q=i&31 (8B bf16 chunks) ----
    // consecutive lanes -> consecutive q -> conflict-free LDS writes,
    // ~8 independent 16B global loads in flight per thread.
    const float4* __restrict__ emb4 = reinterpret_cast<const float4*>(emb);
    uint2* xs2 = reinterpret_cast<uint2*>(xs);
    #pragma unroll
    for (int i = tid; i < ROWS * 32; i += 256) {
        const int r = i >> 5;
        const int q = i & 31;
        const int t = p0 + r;
        uint lo = 0, hi = 0;
        if (t < SEQL && q < 25) {
            const int tok = words[b * SEQL + t];
            float4 x = emb4[(long)tok * 25 + q];
            lo = (uint)bf16bits(x.x) | ((uint)bf16bits(x.y) << 16);
            hi = (uint)bf16bits(x.z) | ((uint)bf16bits(x.w) << 16);
        }
        const int addr = (r * 256 + q * 8) ^ ((r & 7) << 4);
        xs2[addr >> 3] = make_uint2(lo, hi);
    }
    __syncthreads();

    // ---- MFMA: wave computes 16 positions x 16 channels, K=640 ----
    f32x4 acc = {0.f, 0.f, 0.f, 0.f};
    const int m0 = wv * 16 + (l & 15);
    const int dl = (l >> 4) << 3;                // k-slice d-offset: 0,8,16,24
    const char* xsb = reinterpret_cast<const char*>(xs);
    #pragma unroll
    for (int ks = 0; ks < KSTEPS; ++ks) {
        const int j  = ks >> 2;
        const int d0 = ((ks & 3) << 5) + dl;
        const int row = m0 + j;
        const int aad = (row * 256 + d0 * 2) ^ ((row & 7) << 4);
        bf16x8 a = *reinterpret_cast<const bf16x8*>(xsb + aad);
        bf16x8 bf = *reinterpret_cast<const bf16x8*>(ws + (ks * 64 + l) * 16);
        acc = __builtin_amdgcn_mfma_f32_16x16x32_bf16(a, bf, acc, 0, 0, 0);
    }

    // ---- bias + relu + masked max over this wave's 4 (pos-group) rows ----
    const int ch  = l & 15;
    const int kch = 2 + (ch >= 2) + (ch >= 5) + (ch >= 9);
    const float bias = *reinterpret_cast<const float*>(ws + BIAS_OFF + ch * 4);
    const int rbase = (l >> 4) << 2;
    float v = 0.f;
    #pragma unroll
    for (int r = 0; r < 4; ++r) {
        const int t = p0 + wv * 16 + rbase + r;       // C row = (lane>>4)*4+reg
        if (t + kch <= SEQL) v = fmaxf(v, fmaxf(acc[r] + bias, 0.f));
    }
    v = fmaxf(v, __shfl_xor(v, 16, 64));
    v = fmaxf(v, __shfl_xor(v, 32, 64));
    if (l < 16) red[wv][ch] = v;
    __syncthreads();

    if (tid < 16) {
        float f = fmaxf(fmaxf(red[0][tid], red[1][tid]),
                        fmaxf(red[2][tid], red[3][tid]));
        feats[bid * 16 + tid] = f;
    }
}

// ---------------- FC: combine 8 block-partials per row, tiny GEMV
__global__ void fc_kernel(const float* __restrict__ feats,
                          const float* __restrict__ fcw,
                          const float* __restrict__ fcb,
                          float* __restrict__ out)
{
    const int i = blockIdx.x * 256 + threadIdx.x;
    if (i >= BATCH * NCLS) return;
    const int b   = i / NCLS;
    const int cls = i - b * NCLS;
    const float* fb = feats + b * (16 * BLKS_PER_ROW);
    float acc = fcb[cls];
    #pragma unroll
    for (int o = 0; o < NCH; ++o) {
        float f = fb[o];
        #pragma unroll
        for (int w = 1; w < BLKS_PER_ROW; ++w) f = fmaxf(f, fb[w * 16 + o]);
        acc += fcw[cls * NCH + o] * f;
    }
    out[i] = acc;
}

extern "C" void kernel_launch(void* const* d_in, const int* in_sizes, int n_in,
                              void* d_out, int out_size, void* d_ws, size_t ws_size,
                              hipStream_t stream) {
    const int*   words = (const int*)  d_in[0];
    const float* emb   = (const float*)d_in[1];
    const float* w2    = (const float*)d_in[2];
    const float* b2    = (const float*)d_in[3];
    const float* w3    = (const float*)d_in[4];
    const float* b3    = (const float*)d_in[5];
    const float* w4    = (const float*)d_in[6];
    const float* b4    = (const float*)d_in[7];
    const float* w5    = (const float*)d_in[8];
    const float* b5    = (const float*)d_in[9];
    const float* fcw   = (const float*)d_in[10];
    const float* fcb   = (const float*)d_in[11];
    float* out = (float*)d_out;
    char*  ws  = (char*)d_ws;

    unsigned short* wsb  = (unsigned short*)ws;
    float* biasf = (float*)(ws + BIAS_OFF);
    float* feats = (float*)(ws + FEAT_OFF);

    hipLaunchKernelGGL(repack_w, dim3(40), dim3(256), 0, stream,
                       w2, b2, w3, b3, w4, b4, w5, b5, wsb, biasf);
    hipLaunchKernelGGL(cnn_mfma, dim3(NBLK), dim3(256), 0, stream,
                       words, emb, ws, feats);
    hipLaunchKernelGGL(fc_kernel, dim3((BATCH * NCLS + 255) / 256), dim3(256), 0, stream,
                       feats, fcw, fcb, out);
}